// Round 6
// baseline (131.453 us; speedup 1.0000x reference)
//
#include <hip/hip_runtime.h>
#include <float.h>
#include <math.h>

// ---------------------------------------------------------------------------
// DRR via Siddon ray casting.  NX=NY=NZ=192, H=W=192, SDR=300, DELX=DELY=2,
// SPACING=1, BAM=1, B=2, N_SUB=18432.
// Graph (4 nodes): memset(out) -> reduce (block partials, no atomics) ->
// setup (single block: final reduce + LDS mark + tile count/scan/emit) ->
// ray (exact per-step midpoint voxel pick, reciprocal-mul alpha updates,
// 16 alpha-chunks per ray, wave = 64 consecutive tile-ordered pixels).
//
// Perf history:
//   r1 reduce=146us / r4 reduce=64us: same-cache-line atomic serialization
//     (~12ns/atomic); fixed by two-stage plain-store reduction (r5).
//   r3 FAIL: incremental alpha (drift) + linear-addr clamp (row wrap).
//     Voxel MUST be recomputed from segment midpoint each step (r4 passes).
//   r5->r6: 9 graph nodes -> 4 (inter-dispatch gaps ~3-6us each).
// ---------------------------------------------------------------------------

#define NDIM   192
#define HW     (NDIM * NDIM)          // 36864
#define NSUB   (HW / 2)               // 18432
#define NTILE  576                    // 8x8 detector tiles
#define NBATCH 2
#define NCHUNK 16
#define NVOX   (NDIM * NDIM * NDIM)   // 7077888
#define SDRF   300.0f
#define RBLK   1728                   // reduce blocks: 1728*256*4 f4 == NVOX/4

// ws layout (bytes):
//   [0..12)                    final {smin, rmin, rmax}
//   [16 .. 16+4*NSUB)          list (tile-ordered selected pixels)
//   [.. +4*3*RBLK)             block partials: smin[RBLK], rmin[RBLK], rmax[RBLK]
#define WS_LIST_OFF 16
#define WS_PART_OFF (WS_LIST_OFF + 4 * NSUB)

// --------------------------- reduction stage 1 -----------------------------
// soft_min over (-800, 350]; rmin/rmax over v > -800 (BAM==1 -> identity).
// Each block stores 3 partials to DISTINCT slots (no atomics).
__global__ __launch_bounds__(256) void reduce_kernel(
    const float* __restrict__ vol, float* __restrict__ parts) {
    const int tid = blockIdx.x * 256 + threadIdx.x;
    const float4* __restrict__ v4 = (const float4*)vol;
    const int S = RBLK * 256;         // 442368

    float4 r0 = v4[tid + 0 * S];
    float4 r1 = v4[tid + 1 * S];
    float4 r2 = v4[tid + 2 * S];
    float4 r3 = v4[tid + 3 * S];

    float smin = FLT_MAX, rmin = FLT_MAX, rmax = -FLT_MAX;
    float4 rr[4] = {r0, r1, r2, r3};
#pragma unroll
    for (int k = 0; k < 4; ++k) {
        float xs[4] = {rr[k].x, rr[k].y, rr[k].z, rr[k].w};
#pragma unroll
        for (int j = 0; j < 4; ++j) {
            float x = xs[j];
            bool in = (x > -800.0f);
            rmin = fminf(rmin, in ? x : FLT_MAX);
            rmax = fmaxf(rmax, in ? x : -FLT_MAX);
            smin = fminf(smin, (in && x <= 350.0f) ? x : FLT_MAX);
        }
    }
#pragma unroll
    for (int off = 32; off > 0; off >>= 1) {
        smin = fminf(smin, __shfl_down(smin, off));
        rmin = fminf(rmin, __shfl_down(rmin, off));
        rmax = fmaxf(rmax, __shfl_down(rmax, off));
    }
    __shared__ float sm[4], rm[4], rx[4];
    int w = threadIdx.x >> 6;
    if ((threadIdx.x & 63) == 0) { sm[w] = smin; rm[w] = rmin; rx[w] = rmax; }
    __syncthreads();
    if (threadIdx.x == 0) {
        parts[blockIdx.x] =
            fminf(fminf(sm[0], sm[1]), fminf(sm[2], sm[3]));
        parts[RBLK + blockIdx.x] =
            fminf(fminf(rm[0], rm[1]), fminf(rm[2], rm[3]));
        parts[2 * RBLK + blockIdx.x] =
            fmaxf(fmaxf(rx[0], rx[1]), fmaxf(rx[2], rx[3]));
    }
}

// --------------------------- fused setup -----------------------------------
// Single block, 1024 threads.  Does:
//   (a) final min/max fold of the 1728 block partials -> ws[0..2]
//   (b) mark selected pixels in LDS (no global mark array)
//   (c) per-8x8-tile count -> prefix scan -> tile-ordered compact list
// key q = tile*64 + lane; 64 consecutive list entries then form ~two compact
// 8x8 detector patches -> coherent gather front in ray_kernel.
__device__ __forceinline__ int key_to_pixel(int tile, int lane) {
    int pi = (tile / 24) * 8 + (lane >> 3);
    int pj = (tile % 24) * 8 + (lane & 7);
    return pi * NDIM + pj;
}

__global__ __launch_bounds__(1024) void setup_kernel(
    const float* __restrict__ parts, const int* __restrict__ sidx,
    float* __restrict__ wsf, int* __restrict__ list) {
    __shared__ unsigned char smark[HW];   // 36 KB
    __shared__ int s[NTILE];
    __shared__ float sm[16], rm[16], rx[16];
    const int t = threadIdx.x;

    // zero the LDS mark (int4-wide)
    int4* sm4 = (int4*)smark;
    for (int i = t; i < HW / 16; i += 1024) sm4[i] = make_int4(0, 0, 0, 0);

    // (a) fold partials while the zeroing settles
    float smin = FLT_MAX, rmin = FLT_MAX, rmax = -FLT_MAX;
    for (int i = t; i < RBLK; i += 1024) {
        smin = fminf(smin, parts[i]);
        rmin = fminf(rmin, parts[RBLK + i]);
        rmax = fmaxf(rmax, parts[2 * RBLK + i]);
    }
#pragma unroll
    for (int off = 32; off > 0; off >>= 1) {
        smin = fminf(smin, __shfl_down(smin, off));
        rmin = fminf(rmin, __shfl_down(rmin, off));
        rmax = fmaxf(rmax, __shfl_down(rmax, off));
    }
    int w = t >> 6;                       // 16 waves
    if ((t & 63) == 0) { sm[w] = smin; rm[w] = rmin; rx[w] = rmax; }
    __syncthreads();                      // zeroing + partial folds visible

    // (b) mark
    for (int i = t; i < NSUB; i += 1024) smark[sidx[i]] = 1;
    if (t == 0) {
        float a = FLT_MAX, b = FLT_MAX, c = -FLT_MAX;
#pragma unroll
        for (int k = 0; k < 16; ++k) {
            a = fminf(a, sm[k]); b = fminf(b, rm[k]); c = fmaxf(c, rx[k]);
        }
        wsf[0] = a; wsf[1] = b; wsf[2] = c;
    }
    __syncthreads();                      // marks visible

    // (c) count per tile
    int cnt = 0;
    if (t < NTILE) {
#pragma unroll 8
        for (int lane = 0; lane < 64; ++lane)
            cnt += smark[key_to_pixel(t, lane)];
        s[t] = cnt;
    }
    __syncthreads();
    // inclusive Hillis-Steele scan over 576 entries
    for (int off = 1; off < NTILE; off <<= 1) {
        int v = 0, u = 0;
        if (t < NTILE) {
            v = s[t];
            u = (t >= off) ? s[t - off] : 0;
        }
        __syncthreads();
        if (t < NTILE) s[t] = v + u;
        __syncthreads();
    }
    // emit, tile-parallel
    if (t < NTILE) {
        int pos = s[t] - cnt;             // exclusive prefix
        for (int lane = 0; lane < 64; ++lane) {
            int p = key_to_pixel(t, lane);
            if (smark[p]) list[pos++] = p;
        }
    }
}

// --------------------------- axis iterator init ----------------------------
// First plane index (walking toward increasing alpha) whose
// alpha = (i - s)/d is STRICTLY greater than a_lo.  Exact divides (once).
__device__ __forceinline__ void init_axis(float s, float d, float a_lo,
                                          int& i, int& st, float& na) {
    if (d > 0.0f) {
        st = 1;
        float f = s + a_lo * d;
        int ii = (int)floorf(f) + 1;
        ii = max(0, min(ii, NDIM + 1));
        while (ii <= NDIM && ((float)ii - s) / d <= a_lo) ++ii;
        while (ii > 0 && ((float)(ii - 1) - s) / d > a_lo) --ii;
        i  = ii;
        na = (ii <= NDIM) ? ((float)ii - s) / d : FLT_MAX;
    } else {
        st = -1;
        float f = s + a_lo * d;
        int ii = (int)ceilf(f) - 1;
        ii = max(-1, min(ii, NDIM));
        while (ii >= 0 && ((float)ii - s) / d <= a_lo) --ii;
        while (ii < NDIM && ((float)(ii + 1) - s) / d > a_lo) ++ii;
        i  = ii;
        na = (ii >= 0) ? ((float)ii - s) / d : FLT_MAX;
    }
}

// --------------------------- ray kernel ------------------------------------
// Wave = 64 consecutive list entries (compact detector patches).
// grid = (NSUB/256, NCHUNK, NBATCH), block = 256 (4 waves).
// Per step: exact midpoint voxel pick (matches reference); alpha crossings
// recomputed from integer plane index via reciprocal-mul (no drift).
// Loop ordered so the gather issues before the alpha-state update: one full
// iteration of independent VALU work covers the load->acc latency.
__global__ __launch_bounds__(256) void ray_kernel(
    const float* __restrict__ vol, const float* __restrict__ rot,
    const float* __restrict__ trans, const float* __restrict__ wsc,
    const int* __restrict__ list, float* __restrict__ out) {
    const int n = blockIdx.x * 256 + threadIdx.x;
    const int c = blockIdx.y;
    const int b = blockIdx.z;

    const int p  = list[n];
    const int pi = p / NDIM;
    const int pj = p % NDIM;

    // density normalization constants
    float smin = wsc[0];
    float rmin = wsc[1];
    float rmax = wsc[2];
    float dmin = fminf(smin, rmin);
    float dmax = fmaxf(smin, rmax);
    float scale = 1.0f / (dmax - dmin);

    // rotation R = Rz(r0) @ Ry(r1) @ Rx(r2)
    float rz = rot[b * 3 + 0], ry = rot[b * 3 + 1], rx = rot[b * 3 + 2];
    float cz = cosf(rz), sz = sinf(rz);
    float cy = cosf(ry), sy = sinf(ry);
    float cx = cosf(rx), sx = sinf(rx);
    float R00 = cz * cy;
    float R01 = cz * sy * sx - sz * cx;
    float R02 = sz * sx + cz * sy * cx;
    float R10 = sz * cy;
    float R11 = cz * cx + sz * sy * sx;
    float R12 = sz * sy * cx - cz * sx;
    float R20 = -sy;
    float R21 = cy * sx;
    float R22 = cy * cx;
    float tx = trans[b * 3 + 0] + 96.0f;
    float ty = trans[b * 3 + 1] + 96.0f;
    float tz = trans[b * 3 + 2] + 96.0f;

    float srcx = R02 * SDRF + tx;
    float srcy = R12 * SDRF + ty;
    float srcz = R22 * SDRF + tz;
    float gx = ((float)pj - 95.5f) * 2.0f;
    float gy = ((float)pi - 95.5f) * 2.0f;
    float tgx = R00 * gx + R01 * gy + R02 * (-SDRF) + tx;
    float tgy = R10 * gx + R11 * gy + R12 * (-SDRF) + ty;
    float tgz = R20 * gx + R21 * gy + R22 * (-SDRF) + tz;

    float sdx = tgx - srcx, sdy = tgy - srcy, sdz = tgz - srcz;
    float dsx = (sdx == 0.0f) ? 1e-9f : sdx;
    float dsy = (sdy == 0.0f) ? 1e-9f : sdy;
    float dsz = (sdz == 0.0f) ? 1e-9f : sdz;

    float af0 = (0.0f - srcx) / dsx, al0 = (192.0f - srcx) / dsx;
    float af1 = (0.0f - srcy) / dsy, al1 = (192.0f - srcy) / dsy;
    float af2 = (0.0f - srcz) / dsz, al2 = (192.0f - srcz) / dsz;
    float amin = fmaxf(fmaxf(fminf(af0, al0), fminf(af1, al1)), fminf(af2, al2));
    amin = fmaxf(amin, 0.0f);
    float amax = fminf(fminf(fmaxf(af0, al0), fmaxf(af1, al1)), fmaxf(af2, al2));
    amax = fminf(amax, 1.0f);
    amax = fmaxf(amax, amin);
    float ray_len = sqrtf(sdx * sdx + sdy * sdy + sdz * sdz);

    // alpha sub-interval of this chunk
    float span = amax - amin;
    float a_lo = amin + span * ((float)c / (float)NCHUNK);
    float a_hi = (c == NCHUNK - 1) ? amax
                                   : amin + span * ((float)(c + 1) / (float)NCHUNK);

    int i0, i1, i2, st0, st1, st2;
    float na0, na1, na2;
    init_axis(srcx, dsx, a_lo, i0, st0, na0);
    init_axis(srcy, dsy, a_lo, i1, st1, na1);
    init_axis(srcz, dsz, a_lo, i2, st2, na2);

    // reciprocals (IEEE divide once per thread) and float-index trackers
    float r0 = 1.0f / dsx, r1 = 1.0f / dsy, r2 = 1.0f / dsz;
    float fi0 = (float)i0, fi1 = (float)i1, fi2 = (float)i2;
    float fs0 = (float)st0, fs1 = (float)st1, fs2 = (float)st2;

    float cur = a_lo;
    float acc = 0.0f;                 // sum of step * raw_density
    bool fin = false;
    while (!fin) {
        float an  = fminf(fminf(na0, na1), na2);
        fin = !(an < a_hi);
        float a2  = fin ? a_hi : an;
        float mid = 0.5f * (cur + a2);
        float px = fmaf(mid, sdx, srcx);
        float py = fmaf(mid, sdy, srcy);
        float pz = fmaf(mid, sdz, srcz);
        // truncation == floor after the >=0 clamp (see reference clip)
        int ix = min(max((int)px, 0), NDIM - 1);
        int iy = min(max((int)py, 0), NDIM - 1);
        int iz = min(max((int)pz, 0), NDIM - 1);
        int addr = (NDIM - 1) * HW - ix * HW + iy * NDIM + iz;  // flip axis 0
        float v  = vol[addr];         // issue gather early
        // alpha-state update for the NEXT segment (independent of v);
        // harmless on the final iteration (results discarded).
        bool c0 = (na0 == an), c1 = (na1 == an), c2 = (na2 == an);
        float nf0 = fi0 + fs0, nf1 = fi1 + fs1, nf2 = fi2 + fs2;
        float nn0 = (nf0 - srcx) * r0;
        float nn1 = (nf1 - srcy) * r1;
        float nn2 = (nf2 - srcz) * r2;
        fi0 = c0 ? nf0 : fi0;  na0 = c0 ? nn0 : na0;
        fi1 = c1 ? nf1 : fi1;  na1 = c1 ? nn1 : na1;
        fi2 = c2 ? nf2 : fi2;  na2 = c2 ? nn2 : na2;
        // consume gather
        float dv = (v <= -800.0f) ? smin : v;
        acc = fmaf(a2 - cur, dv, acc);
        cur = a2;
    }
    // sum step*(dv - dmin)*scale == scale*(acc - dmin*(a_hi - a_lo))
    float res = (acc - dmin * (a_hi - a_lo)) * scale * ray_len;
    atomicAdd(&out[b * HW + p], res);
}

// --------------------------- launch ----------------------------------------
extern "C" void kernel_launch(void* const* d_in, const int* in_sizes, int n_in,
                              void* d_out, int out_size, void* d_ws,
                              size_t ws_size, hipStream_t stream) {
    const float* vol   = (const float*)d_in[0];
    const float* rot   = (const float*)d_in[1];
    const float* trans = (const float*)d_in[2];
    const int*   sidx  = (const int*)d_in[3];
    float* out = (float*)d_out;

    float* wsf   = (float*)d_ws;
    int*   list  = (int*)((unsigned char*)d_ws + WS_LIST_OFF);
    float* parts = (float*)((unsigned char*)d_ws + WS_PART_OFF);

    hipMemsetAsync(d_out, 0, (size_t)out_size * sizeof(float), stream);
    reduce_kernel<<<RBLK, 256, 0, stream>>>(vol, parts);
    setup_kernel<<<1, 1024, 0, stream>>>(parts, sidx, wsf, list);
    dim3 rgrid(NSUB / 256, NCHUNK, NBATCH);
    ray_kernel<<<rgrid, 256, 0, stream>>>(vol, rot, trans, wsf, list, out);
}